// Round 1
// baseline (1316.898 us; speedup 1.0000x reference)
//
#include <hip/hip_runtime.h>

#define NN 131072        // nodes
#define EE 2097152       // edges
#define SS 32            // channels
#define HH 16            // hidden
#define BB 4096          // graphs
#define EPS 1e-5f

// ---------------- CSR build: histogram, scan, scatter ----------------
__global__ __launch_bounds__(256) void k_hist(const int* __restrict__ ei, int* __restrict__ deg) {
    int e = blockIdx.x * 256 + threadIdx.x;
    if (e < EE) atomicAdd(&deg[ei[EE + e]], 1);
}

__global__ __launch_bounds__(256) void k_scan1(const int* __restrict__ deg, int* __restrict__ off,
                                               int* __restrict__ bsum) {
    __shared__ int s[256];
    int t = threadIdx.x;
    int base = blockIdx.x * 1024 + t * 4;
    int a0 = deg[base], a1 = deg[base + 1], a2 = deg[base + 2], a3 = deg[base + 3];
    int tot = a0 + a1 + a2 + a3;
    s[t] = tot;
    __syncthreads();
    for (int d = 1; d < 256; d <<= 1) {
        int v = (t >= d) ? s[t - d] : 0;
        __syncthreads();
        s[t] += v;
        __syncthreads();
    }
    int excl = s[t] - tot;
    if (t == 255) bsum[blockIdx.x] = s[255];
    off[base] = excl;
    off[base + 1] = excl + a0;
    off[base + 2] = excl + a0 + a1;
    off[base + 3] = excl + a0 + a1 + a2;
}

__global__ __launch_bounds__(128) void k_scan2(int* __restrict__ bsum) {
    __shared__ int s[128];
    int t = threadIdx.x;
    int val = bsum[t];
    s[t] = val;
    __syncthreads();
    for (int d = 1; d < 128; d <<= 1) {
        int v = (t >= d) ? s[t - d] : 0;
        __syncthreads();
        s[t] += v;
        __syncthreads();
    }
    bsum[t] = s[t] - val;   // exclusive
}

__global__ __launch_bounds__(256) void k_scan3(int* __restrict__ off, const int* __restrict__ bsum,
                                               int* __restrict__ cursor) {
    int t = threadIdx.x;
    int base = blockIdx.x * 1024 + t * 4;
    int addv = bsum[blockIdx.x];
#pragma unroll
    for (int i = 0; i < 4; ++i) {
        int v = off[base + i] + addv;
        off[base + i] = v;
        cursor[base + i] = v;
    }
    if (blockIdx.x == 0 && t == 0) off[NN] = EE;
}

__global__ __launch_bounds__(256) void k_scatter(const int* __restrict__ ei, int* __restrict__ cursor,
                                                 int* __restrict__ ssrc) {
    int e = blockIdx.x * 256 + threadIdx.x;
    if (e < EE) {
        int d = ei[EE + e];
        int p = atomicAdd(&cursor[d], 1);
        ssrc[p] = ei[e];
    }
}

// ---------------- per-node pre-transform (u = x@(Wt-Wb)+b1, v = x@Wb) ----------------
// layer 1: F=2 input features
__global__ __launch_bounds__(256) void k_pre1(const float* __restrict__ x, const float* __restrict__ W1,
                                              const float* __restrict__ b1, float* __restrict__ u,
                                              float* __restrict__ v) {
    int t = blockIdx.x * 256 + threadIdx.x;     // N*16 threads
    int n = t >> 4, c = t & 15;
    float x0 = x[n * 2], x1 = x[n * 2 + 1];
    float w0 = W1[c], w1 = W1[16 + c], w2 = W1[32 + c], w3 = W1[48 + c];
    u[t] = b1[c] + x0 * (w0 - w2) + x1 * (w1 - w3);
    v[t] = x0 * w2 + x1 * w3;
}

// layers 2/3: F=32 input features
__global__ __launch_bounds__(256) void k_pre32(const float* __restrict__ h, const float* __restrict__ W1,
                                               const float* __restrict__ b1, float* __restrict__ u,
                                               float* __restrict__ v) {
    __shared__ float sh[16][33];
    __shared__ float wd[32][16];
    __shared__ float wv[32][16];
    int t = threadIdx.x;
    for (int i = t; i < 512; i += 256) {
        int f = i >> 4, c = i & 15;
        float wt = W1[i];            // rows 0..31 (x_i part)
        float wb = W1[512 + i];      // rows 32..63 (x_j - x_i part)
        wd[f][c] = wt - wb;
        wv[f][c] = wb;
    }
    int nb = blockIdx.x * 16;
    for (int i = t; i < 512; i += 256) sh[i >> 5][i & 31] = h[nb * 32 + i];
    __syncthreads();
    int c = t & 15, nl = t >> 4;
    float uu = b1[c], vv = 0.f;
#pragma unroll
    for (int f = 0; f < 32; ++f) {
        float hv = sh[nl][f];
        uu += hv * wd[f][c];
        vv += hv * wv[f][c];
    }
    int n = nb + nl;
    u[n * 16 + c] = uu;
    v[n * 16 + c] = vv;
}

// ---------------- gather (CSR reduce of ReLU(u[dst]+v[src])) + @W2 + BN partial sums ----------------
__global__ __launch_bounds__(256) void k_gather(const float* __restrict__ u, const float* __restrict__ v,
                                                const int* __restrict__ ssrc, const int* __restrict__ off,
                                                const float* __restrict__ W2, const float* __restrict__ b2,
                                                float* __restrict__ y, float* __restrict__ bns) {
    __shared__ float sw2[16][32];
    __shared__ float sagg[16][17];
    __shared__ float sy[32][17];
    int t = threadIdx.x;
    for (int i = t; i < 512; i += 256) sw2[i >> 5][i & 31] = W2[i];
    int c = t & 15, nl = t >> 4;
    int n = blockIdx.x * 16 + nl;
    int s0 = off[n], e0 = off[n + 1];
    float uc = u[n * 16 + c];
    float acc = 0.f;
    for (int p = s0; p < e0; ++p) {
        int src = ssrc[p];
        acc += fmaxf(uc + v[src * 16 + c], 0.f);
    }
    sagg[nl][c] = acc;
    __syncthreads();
    float cnt = (float)(e0 - s0);
    float y0 = b2[c] * cnt, y1 = b2[c + 16] * cnt;
#pragma unroll
    for (int k = 0; k < 16; ++k) {
        float a = sagg[nl][k];
        y0 += a * sw2[k][c];
        y1 += a * sw2[k][c + 16];
    }
    y[n * 32 + c] = y0;
    y[n * 32 + 16 + c] = y1;
    sy[c][nl] = y0;
    sy[c + 16][nl] = y1;
    __syncthreads();
    if (t < 32) {
        float sm = 0.f, sq = 0.f;
#pragma unroll
        for (int k2 = 0; k2 < 16; ++k2) {
            float w = sy[t][k2];
            sm += w;
            sq += w * w;
        }
        atomicAdd(&bns[t], sm);
        atomicAdd(&bns[32 + t], sq);
    }
}

// ---------------- BN (training-mode batch stats) + ReLU ----------------
__global__ __launch_bounds__(256) void k_bnrelu(const float* __restrict__ y, const float* __restrict__ bns,
                                                const float* __restrict__ g, const float* __restrict__ bb,
                                                float* __restrict__ h) {
    int t = blockIdx.x * 256 + threadIdx.x;
    int j = t & 31;
    const float inv_n = 1.0f / (float)NN;
    float mean = bns[j] * inv_n;
    float var = bns[32 + j] * inv_n - mean * mean;
    float sc = g[j] * rsqrtf(var + EPS);
    float sh = bb[j] - mean * sc;
    h[t] = fmaxf(y[t] * sc + sh, 0.f);
}

// ---------------- fp32 tiled GEMM: C = relu(A[M,K]@B[K,N] + bias) ----------------
#define GBM 64
#define GBN 64
#define GBK 16
__global__ __launch_bounds__(256) void k_gemm(const float* __restrict__ A, const float* __restrict__ Bm,
                                              const float* __restrict__ bias, float* __restrict__ C,
                                              int M, int Nc, int K, int relu) {
    __shared__ float As[GBK][GBM + 4];
    __shared__ float Bs[GBK][GBN + 4];
    int tid = threadIdx.x;
    int tx = tid & 15;
    int ty = tid >> 4;
    int rowBase = blockIdx.x * GBM;
    int colBase = blockIdx.y * GBN;
    int lr = tid >> 2;
    int lk = (tid & 3) * 4;
    int bkr = tid >> 4;
    int bc = (tid & 15) * 4;
    float acc[4][4] = {};
    for (int kt = 0; kt < K; kt += GBK) {
        float4 av = *(const float4*)(A + (size_t)(rowBase + lr) * K + kt + lk);
        As[lk + 0][lr] = av.x;
        As[lk + 1][lr] = av.y;
        As[lk + 2][lr] = av.z;
        As[lk + 3][lr] = av.w;
        float4 bv = *(const float4*)(Bm + (size_t)(kt + bkr) * Nc + colBase + bc);
        *(float4*)&Bs[bkr][bc] = bv;
        __syncthreads();
#pragma unroll
        for (int k = 0; k < GBK; ++k) {
            float4 ar = *(const float4*)&As[k][ty * 4];
            float4 br = *(const float4*)&Bs[k][tx * 4];
            acc[0][0] += ar.x * br.x; acc[0][1] += ar.x * br.y; acc[0][2] += ar.x * br.z; acc[0][3] += ar.x * br.w;
            acc[1][0] += ar.y * br.x; acc[1][1] += ar.y * br.y; acc[1][2] += ar.y * br.z; acc[1][3] += ar.y * br.w;
            acc[2][0] += ar.z * br.x; acc[2][1] += ar.z * br.y; acc[2][2] += ar.z * br.z; acc[2][3] += ar.z * br.w;
            acc[3][0] += ar.w * br.x; acc[3][1] += ar.w * br.y; acc[3][2] += ar.w * br.z; acc[3][3] += ar.w * br.w;
        }
        __syncthreads();
    }
    float b0 = bias[colBase + tx * 4 + 0];
    float b1 = bias[colBase + tx * 4 + 1];
    float b2 = bias[colBase + tx * 4 + 2];
    float b3 = bias[colBase + tx * 4 + 3];
#pragma unroll
    for (int i = 0; i < 4; ++i) {
        int row = rowBase + ty * 4 + i;
        float4 o;
        o.x = acc[i][0] + b0;
        o.y = acc[i][1] + b1;
        o.z = acc[i][2] + b2;
        o.w = acc[i][3] + b3;
        if (relu) {
            o.x = fmaxf(o.x, 0.f); o.y = fmaxf(o.y, 0.f);
            o.z = fmaxf(o.z, 0.f); o.w = fmaxf(o.w, 0.f);
        }
        *(float4*)(C + (size_t)row * Nc + colBase + tx * 4) = o;
    }
}

// ---------------- dueling head: value + adv - adv.mean ----------------
__global__ __launch_bounds__(64) void k_head(const float* __restrict__ X, const float* __restrict__ vW,
                                             const float* __restrict__ vb, const float* __restrict__ aW,
                                             const float* __restrict__ ab, float* __restrict__ out) {
    __shared__ float s[256];
    __shared__ float sval;
    int b = blockIdx.x, t = threadIdx.x;
    float4 xv = *(const float4*)(X + (size_t)b * 256 + t * 4);
    *(float4*)&s[t * 4] = xv;
    float pv = xv.x * vW[t * 4] + xv.y * vW[t * 4 + 1] + xv.z * vW[t * 4 + 2] + xv.w * vW[t * 4 + 3];
#pragma unroll
    for (int d = 32; d > 0; d >>= 1) pv += __shfl_down(pv, d, 64);
    if (t == 0) sval = pv + vb[0];
    __syncthreads();
    int n = t >> 1, a = t & 1;
    const float* wp = aW + n * 512 + a;
    float acc = 0.f;
#pragma unroll 8
    for (int f = 0; f < 256; ++f) acc += s[f] * wp[f * 2];
    float adv = acc + ab[n * 2 + a];
    float other = __shfl_xor(adv, 1, 64);
    out[(size_t)b * 64 + t] = sval + 0.5f * (adv - other);
}

extern "C" void kernel_launch(void* const* d_in, const int* in_sizes, int n_in,
                              void* d_out, int out_size, void* d_ws, size_t ws_size,
                              hipStream_t stream) {
    const float* x    = (const float*)d_in[0];
    const int*   ei   = (const int*)d_in[1];
    const float* c1W1 = (const float*)d_in[2];
    const float* c1b1 = (const float*)d_in[3];
    const float* c1W2 = (const float*)d_in[4];
    const float* c1b2 = (const float*)d_in[5];
    const float* c2W1 = (const float*)d_in[6];
    const float* c2b1 = (const float*)d_in[7];
    const float* c2W2 = (const float*)d_in[8];
    const float* c2b2 = (const float*)d_in[9];
    const float* c3W1 = (const float*)d_in[10];
    const float* c3b1 = (const float*)d_in[11];
    const float* c3W2 = (const float*)d_in[12];
    const float* c3b2 = (const float*)d_in[13];
    const float* bn_g = (const float*)d_in[14];
    const float* bn_b = (const float*)d_in[15];
    const float* mW1  = (const float*)d_in[16];
    const float* mb1  = (const float*)d_in[17];
    const float* mW2  = (const float*)d_in[18];
    const float* mb2  = (const float*)d_in[19];
    const float* mW3  = (const float*)d_in[20];
    const float* mb3  = (const float*)d_in[21];
    const float* vW   = (const float*)d_in[22];
    const float* vb   = (const float*)d_in[23];
    const float* aW   = (const float*)d_in[24];
    const float* ab   = (const float*)d_in[25];
    float* out = (float*)d_out;

    char* p = (char*)d_ws;
    auto take = [&](size_t bytes) {
        char* r = p;
        p += (bytes + 255) & ~(size_t)255;
        return r;
    };
    int*   deg    = (int*)take((size_t)NN * 4);
    int*   off    = (int*)take((size_t)(NN + 1) * 4);
    int*   bsum   = (int*)take(512);
    int*   cursor = (int*)take((size_t)NN * 4);
    int*   ssrc   = (int*)take((size_t)EE * 4);
    float* u      = (float*)take((size_t)NN * HH * 4);
    float* v      = (float*)take((size_t)NN * HH * 4);
    float* y      = (float*)take((size_t)NN * SS * 4);
    float* h      = (float*)take((size_t)NN * SS * 4);
    float* bns    = (float*)take(3 * 64 * 4);
    // X1/X2 reuse the y buffer (dead after last bn_relu): 4096*256*4 = 4 MB each
    float* X1 = y;
    float* X2 = y + (size_t)BB * 256;

    hipMemsetAsync(deg, 0, (size_t)NN * 4, stream);
    hipMemsetAsync(bns, 0, 3 * 64 * 4, stream);

    // CSR build (reused by all 3 conv layers)
    k_hist<<<EE / 256, 256, 0, stream>>>(ei, deg);
    k_scan1<<<128, 256, 0, stream>>>(deg, off, bsum);
    k_scan2<<<1, 128, 0, stream>>>(bsum);
    k_scan3<<<128, 256, 0, stream>>>(off, bsum, cursor);
    k_scatter<<<EE / 256, 256, 0, stream>>>(ei, cursor, ssrc);

    // layer 1
    k_pre1<<<NN * 16 / 256, 256, 0, stream>>>(x, c1W1, c1b1, u, v);
    k_gather<<<NN / 16, 256, 0, stream>>>(u, v, ssrc, off, c1W2, c1b2, y, bns);
    k_bnrelu<<<NN * 32 / 256, 256, 0, stream>>>(y, bns, bn_g, bn_b, h);
    // layer 2
    k_pre32<<<NN / 16, 256, 0, stream>>>(h, c2W1, c2b1, u, v);
    k_gather<<<NN / 16, 256, 0, stream>>>(u, v, ssrc, off, c2W2, c2b2, y, bns + 64);
    k_bnrelu<<<NN * 32 / 256, 256, 0, stream>>>(y, bns + 64, bn_g + 32, bn_b + 32, h);
    // layer 3
    k_pre32<<<NN / 16, 256, 0, stream>>>(h, c3W1, c3b1, u, v);
    k_gather<<<NN / 16, 256, 0, stream>>>(u, v, ssrc, off, c3W2, c3b2, y, bns + 128);
    k_bnrelu<<<NN * 32 / 256, 256, 0, stream>>>(y, bns + 128, bn_g + 64, bn_b + 64, h);

    // dense head MLP (h is [4096,1024] row-major by construction)
    k_gemm<<<dim3(BB / GBM, 256 / GBN), 256, 0, stream>>>(h, mW1, mb1, X1, BB, 256, 1024, 1);
    k_gemm<<<dim3(BB / GBM, 256 / GBN), 256, 0, stream>>>(X1, mW2, mb2, X2, BB, 256, 256, 1);
    k_gemm<<<dim3(BB / GBM, 256 / GBN), 256, 0, stream>>>(X2, mW3, mb3, X1, BB, 256, 256, 1);

    // dueling heads
    k_head<<<BB, 64, 0, stream>>>(X1, vW, vb, aW, ab, out);
}

// Round 2
// 1285.441 us; speedup vs baseline: 1.0245x; 1.0245x over previous
//
#include <hip/hip_runtime.h>

#define NN 131072        // nodes
#define EE 2097152       // edges
#define SS 32            // channels
#define HH 16            // hidden
#define BB 4096          // graphs
#define EPS 1e-5f

// ---------------- CSR build: histogram, scan, scatter ----------------
__global__ __launch_bounds__(256) void k_hist(const int* __restrict__ ei, int* __restrict__ deg) {
    int e = blockIdx.x * 256 + threadIdx.x;
    if (e < EE) atomicAdd(&deg[ei[EE + e]], 1);
}

__global__ __launch_bounds__(256) void k_scan1(const int* __restrict__ deg, int* __restrict__ off,
                                               int* __restrict__ bsum) {
    __shared__ int s[256];
    int t = threadIdx.x;
    int base = blockIdx.x * 1024 + t * 4;
    int a0 = deg[base], a1 = deg[base + 1], a2 = deg[base + 2], a3 = deg[base + 3];
    int tot = a0 + a1 + a2 + a3;
    s[t] = tot;
    __syncthreads();
    for (int d = 1; d < 256; d <<= 1) {
        int v = (t >= d) ? s[t - d] : 0;
        __syncthreads();
        s[t] += v;
        __syncthreads();
    }
    int excl = s[t] - tot;
    if (t == 255) bsum[blockIdx.x] = s[255];
    off[base] = excl;
    off[base + 1] = excl + a0;
    off[base + 2] = excl + a0 + a1;
    off[base + 3] = excl + a0 + a1 + a2;
}

__global__ __launch_bounds__(128) void k_scan2(int* __restrict__ bsum) {
    __shared__ int s[128];
    int t = threadIdx.x;
    int val = bsum[t];
    s[t] = val;
    __syncthreads();
    for (int d = 1; d < 128; d <<= 1) {
        int v = (t >= d) ? s[t - d] : 0;
        __syncthreads();
        s[t] += v;
        __syncthreads();
    }
    bsum[t] = s[t] - val;   // exclusive
}

__global__ __launch_bounds__(256) void k_scan3(int* __restrict__ off, const int* __restrict__ bsum,
                                               int* __restrict__ cursor) {
    int t = threadIdx.x;
    int base = blockIdx.x * 1024 + t * 4;
    int addv = bsum[blockIdx.x];
#pragma unroll
    for (int i = 0; i < 4; ++i) {
        int v = off[base + i] + addv;
        off[base + i] = v;
        cursor[base + i] = v;
    }
    if (blockIdx.x == 0 && t == 0) off[NN] = EE;
}

__global__ __launch_bounds__(256) void k_scatter(const int* __restrict__ ei, int* __restrict__ cursor,
                                                 int* __restrict__ ssrc) {
    int e = blockIdx.x * 256 + threadIdx.x;
    if (e < EE) {
        int d = ei[EE + e];
        int p = atomicAdd(&cursor[d], 1);
        ssrc[p] = ei[e];
    }
}

// ---------------- per-node pre-transform (u = x@(Wt-Wb)+b1, v = x@Wb) ----------------
// v has NN+1 rows; row NN is a -1e30 dummy so padded gather slots contribute 0 after ReLU.
__global__ __launch_bounds__(256) void k_pre1(const float* __restrict__ x, const float* __restrict__ W1,
                                              const float* __restrict__ b1, float* __restrict__ u,
                                              float* __restrict__ v) {
    int t = blockIdx.x * 256 + threadIdx.x;     // N*16 threads
    int n = t >> 4, c = t & 15;
    float x0 = x[n * 2], x1 = x[n * 2 + 1];
    float w0 = W1[c], w1 = W1[16 + c], w2 = W1[32 + c], w3 = W1[48 + c];
    u[t] = b1[c] + x0 * (w0 - w2) + x1 * (w1 - w3);
    v[t] = x0 * w2 + x1 * w3;
    if (blockIdx.x == 0 && t < 16) v[NN * 16 + t] = -1e30f;   // dummy row
}

// layers 2/3: F=32 input features
__global__ __launch_bounds__(256) void k_pre32(const float* __restrict__ h, const float* __restrict__ W1,
                                               const float* __restrict__ b1, float* __restrict__ u,
                                               float* __restrict__ v) {
    __shared__ float sh[16][33];
    __shared__ float wd[32][16];
    __shared__ float wv[32][16];
    int t = threadIdx.x;
    for (int i = t; i < 512; i += 256) {
        int f = i >> 4, c = i & 15;
        float wt = W1[i];            // rows 0..31 (x_i part)
        float wb = W1[512 + i];      // rows 32..63 (x_j - x_i part)
        wd[f][c] = wt - wb;
        wv[f][c] = wb;
    }
    int nb = blockIdx.x * 16;
    for (int i = t; i < 512; i += 256) sh[i >> 5][i & 31] = h[nb * 32 + i];
    __syncthreads();
    int c = t & 15, nl = t >> 4;
    float uu = b1[c], vv = 0.f;
#pragma unroll
    for (int f = 0; f < 32; ++f) {
        float hv = sh[nl][f];
        uu += hv * wd[f][c];
        vv += hv * wv[f][c];
    }
    int n = nb + nl;
    u[n * 16 + c] = uu;
    v[n * 16 + c] = vv;
    if (blockIdx.x == 0 && t < 16) v[NN * 16 + t] = -1e30f;   // dummy row
}

// ---------------- gather (CSR reduce of ReLU(u[dst]+v[src])) + @W2 + BN partial sums ----------------
// 8-wide software pipeline: 8 edge indices loaded, then 8 independent v-gathers in
// flight per lane (latency-bound fix; padded slots hit the -1e30 dummy row -> 0).
__global__ __launch_bounds__(256) void k_gather(const float* __restrict__ u, const float* __restrict__ v,
                                                const int* __restrict__ ssrc, const int* __restrict__ off,
                                                const float* __restrict__ W2, const float* __restrict__ b2,
                                                float* __restrict__ y, float* __restrict__ bns) {
    __shared__ float sw2[16][32];
    __shared__ float sagg[16][17];
    __shared__ float sy[32][17];
    int t = threadIdx.x;
    for (int i = t; i < 512; i += 256) sw2[i >> 5][i & 31] = W2[i];
    int c = t & 15, nl = t >> 4;
    int n = blockIdx.x * 16 + nl;
    int s0 = off[n], e0 = off[n + 1];
    float uc = u[n * 16 + c];
    float acc = 0.f;
    for (int p = s0; p < e0; p += 8) {
        int idx[8];
#pragma unroll
        for (int i = 0; i < 8; ++i) idx[i] = (p + i < e0) ? ssrc[p + i] : NN;
        float vv[8];
#pragma unroll
        for (int i = 0; i < 8; ++i) vv[i] = v[idx[i] * 16 + c];
#pragma unroll
        for (int i = 0; i < 8; ++i) acc += fmaxf(uc + vv[i], 0.f);
    }
    sagg[nl][c] = acc;
    __syncthreads();
    float cnt = (float)(e0 - s0);
    float y0 = b2[c] * cnt, y1 = b2[c + 16] * cnt;
#pragma unroll
    for (int k = 0; k < 16; ++k) {
        float a = sagg[nl][k];
        y0 += a * sw2[k][c];
        y1 += a * sw2[k][c + 16];
    }
    y[n * 32 + c] = y0;
    y[n * 32 + 16 + c] = y1;
    sy[c][nl] = y0;
    sy[c + 16][nl] = y1;
    __syncthreads();
    if (t < 32) {
        float sm = 0.f, sq = 0.f;
#pragma unroll
        for (int k2 = 0; k2 < 16; ++k2) {
            float w = sy[t][k2];
            sm += w;
            sq += w * w;
        }
        atomicAdd(&bns[t], sm);
        atomicAdd(&bns[32 + t], sq);
    }
}

// ---------------- BN (training-mode batch stats) + ReLU ----------------
__global__ __launch_bounds__(256) void k_bnrelu(const float* __restrict__ y, const float* __restrict__ bns,
                                                const float* __restrict__ g, const float* __restrict__ bb,
                                                float* __restrict__ h) {
    int t = blockIdx.x * 256 + threadIdx.x;
    int j = t & 31;
    const float inv_n = 1.0f / (float)NN;
    float mean = bns[j] * inv_n;
    float var = bns[32 + j] * inv_n - mean * mean;
    float sc = g[j] * rsqrtf(var + EPS);
    float sh = bb[j] - mean * sc;
    h[t] = fmaxf(y[t] * sc + sh, 0.f);
}

// ---------------- fp32 tiled GEMM: C = relu(A[M,K]@B[K,N] + bias) ----------------
#define GBM 64
#define GBN 64
#define GBK 16
__global__ __launch_bounds__(256) void k_gemm(const float* __restrict__ A, const float* __restrict__ Bm,
                                              const float* __restrict__ bias, float* __restrict__ C,
                                              int M, int Nc, int K, int relu) {
    __shared__ float As[GBK][GBM + 4];
    __shared__ float Bs[GBK][GBN + 4];
    int tid = threadIdx.x;
    int tx = tid & 15;
    int ty = tid >> 4;
    int rowBase = blockIdx.x * GBM;
    int colBase = blockIdx.y * GBN;
    int lr = tid >> 2;
    int lk = (tid & 3) * 4;
    int bkr = tid >> 4;
    int bc = (tid & 15) * 4;
    float acc[4][4] = {};
    for (int kt = 0; kt < K; kt += GBK) {
        float4 av = *(const float4*)(A + (size_t)(rowBase + lr) * K + kt + lk);
        As[lk + 0][lr] = av.x;
        As[lk + 1][lr] = av.y;
        As[lk + 2][lr] = av.z;
        As[lk + 3][lr] = av.w;
        float4 bv = *(const float4*)(Bm + (size_t)(kt + bkr) * Nc + colBase + bc);
        *(float4*)&Bs[bkr][bc] = bv;
        __syncthreads();
#pragma unroll
        for (int k = 0; k < GBK; ++k) {
            float4 ar = *(const float4*)&As[k][ty * 4];
            float4 br = *(const float4*)&Bs[k][tx * 4];
            acc[0][0] += ar.x * br.x; acc[0][1] += ar.x * br.y; acc[0][2] += ar.x * br.z; acc[0][3] += ar.x * br.w;
            acc[1][0] += ar.y * br.x; acc[1][1] += ar.y * br.y; acc[1][2] += ar.y * br.z; acc[1][3] += ar.y * br.w;
            acc[2][0] += ar.z * br.x; acc[2][1] += ar.z * br.y; acc[2][2] += ar.z * br.z; acc[2][3] += ar.z * br.w;
            acc[3][0] += ar.w * br.x; acc[3][1] += ar.w * br.y; acc[3][2] += ar.w * br.z; acc[3][3] += ar.w * br.w;
        }
        __syncthreads();
    }
    float b0 = bias[colBase + tx * 4 + 0];
    float b1 = bias[colBase + tx * 4 + 1];
    float b2 = bias[colBase + tx * 4 + 2];
    float b3 = bias[colBase + tx * 4 + 3];
#pragma unroll
    for (int i = 0; i < 4; ++i) {
        int row = rowBase + ty * 4 + i;
        float4 o;
        o.x = acc[i][0] + b0;
        o.y = acc[i][1] + b1;
        o.z = acc[i][2] + b2;
        o.w = acc[i][3] + b3;
        if (relu) {
            o.x = fmaxf(o.x, 0.f); o.y = fmaxf(o.y, 0.f);
            o.z = fmaxf(o.z, 0.f); o.w = fmaxf(o.w, 0.f);
        }
        *(float4*)(C + (size_t)row * Nc + colBase + tx * 4) = o;
    }
}

// ---------------- dueling head: value + adv - adv.mean ----------------
__global__ __launch_bounds__(64) void k_head(const float* __restrict__ X, const float* __restrict__ vW,
                                             const float* __restrict__ vb, const float* __restrict__ aW,
                                             const float* __restrict__ ab, float* __restrict__ out) {
    __shared__ float s[256];
    __shared__ float sval;
    int b = blockIdx.x, t = threadIdx.x;
    float4 xv = *(const float4*)(X + (size_t)b * 256 + t * 4);
    *(float4*)&s[t * 4] = xv;
    float pv = xv.x * vW[t * 4] + xv.y * vW[t * 4 + 1] + xv.z * vW[t * 4 + 2] + xv.w * vW[t * 4 + 3];
#pragma unroll
    for (int d = 32; d > 0; d >>= 1) pv += __shfl_down(pv, d, 64);
    if (t == 0) sval = pv + vb[0];
    __syncthreads();
    int n = t >> 1, a = t & 1;
    const float* wp = aW + n * 512 + a;
    float acc = 0.f;
#pragma unroll 8
    for (int f = 0; f < 256; ++f) acc += s[f] * wp[f * 2];
    float adv = acc + ab[n * 2 + a];
    float other = __shfl_xor(adv, 1, 64);
    out[(size_t)b * 64 + t] = sval + 0.5f * (adv - other);
}

extern "C" void kernel_launch(void* const* d_in, const int* in_sizes, int n_in,
                              void* d_out, int out_size, void* d_ws, size_t ws_size,
                              hipStream_t stream) {
    const float* x    = (const float*)d_in[0];
    const int*   ei   = (const int*)d_in[1];
    const float* c1W1 = (const float*)d_in[2];
    const float* c1b1 = (const float*)d_in[3];
    const float* c1W2 = (const float*)d_in[4];
    const float* c1b2 = (const float*)d_in[5];
    const float* c2W1 = (const float*)d_in[6];
    const float* c2b1 = (const float*)d_in[7];
    const float* c2W2 = (const float*)d_in[8];
    const float* c2b2 = (const float*)d_in[9];
    const float* c3W1 = (const float*)d_in[10];
    const float* c3b1 = (const float*)d_in[11];
    const float* c3W2 = (const float*)d_in[12];
    const float* c3b2 = (const float*)d_in[13];
    const float* bn_g = (const float*)d_in[14];
    const float* bn_b = (const float*)d_in[15];
    const float* mW1  = (const float*)d_in[16];
    const float* mb1  = (const float*)d_in[17];
    const float* mW2  = (const float*)d_in[18];
    const float* mb2  = (const float*)d_in[19];
    const float* mW3  = (const float*)d_in[20];
    const float* mb3  = (const float*)d_in[21];
    const float* vW   = (const float*)d_in[22];
    const float* vb   = (const float*)d_in[23];
    const float* aW   = (const float*)d_in[24];
    const float* ab   = (const float*)d_in[25];
    float* out = (float*)d_out;

    char* p = (char*)d_ws;
    auto take = [&](size_t bytes) {
        char* r = p;
        p += (bytes + 255) & ~(size_t)255;
        return r;
    };
    int*   deg    = (int*)take((size_t)NN * 4);
    int*   off    = (int*)take((size_t)(NN + 1) * 4);
    int*   bsum   = (int*)take(512);
    int*   cursor = (int*)take((size_t)NN * 4);
    int*   ssrc   = (int*)take((size_t)EE * 4);
    float* u      = (float*)take((size_t)NN * HH * 4);
    float* v      = (float*)take((size_t)(NN + 1) * HH * 4);   // +1 dummy row
    float* y      = (float*)take((size_t)NN * SS * 4);
    float* h      = (float*)take((size_t)NN * SS * 4);
    float* bns    = (float*)take(3 * 64 * 4);
    // X1/X2 reuse the y buffer (dead after last bn_relu): 4096*256*4 = 4 MB each
    float* X1 = y;
    float* X2 = y + (size_t)BB * 256;

    hipMemsetAsync(deg, 0, (size_t)NN * 4, stream);
    hipMemsetAsync(bns, 0, 3 * 64 * 4, stream);

    // CSR build (reused by all 3 conv layers)
    k_hist<<<EE / 256, 256, 0, stream>>>(ei, deg);
    k_scan1<<<128, 256, 0, stream>>>(deg, off, bsum);
    k_scan2<<<1, 128, 0, stream>>>(bsum);
    k_scan3<<<128, 256, 0, stream>>>(off, bsum, cursor);
    k_scatter<<<EE / 256, 256, 0, stream>>>(ei, cursor, ssrc);

    // layer 1
    k_pre1<<<NN * 16 / 256, 256, 0, stream>>>(x, c1W1, c1b1, u, v);
    k_gather<<<NN / 16, 256, 0, stream>>>(u, v, ssrc, off, c1W2, c1b2, y, bns);
    k_bnrelu<<<NN * 32 / 256, 256, 0, stream>>>(y, bns, bn_g, bn_b, h);
    // layer 2
    k_pre32<<<NN / 16, 256, 0, stream>>>(h, c2W1, c2b1, u, v);
    k_gather<<<NN / 16, 256, 0, stream>>>(u, v, ssrc, off, c2W2, c2b2, y, bns + 64);
    k_bnrelu<<<NN * 32 / 256, 256, 0, stream>>>(y, bns + 64, bn_g + 32, bn_b + 32, h);
    // layer 3
    k_pre32<<<NN / 16, 256, 0, stream>>>(h, c3W1, c3b1, u, v);
    k_gather<<<NN / 16, 256, 0, stream>>>(u, v, ssrc, off, c3W2, c3b2, y, bns + 128);
    k_bnrelu<<<NN * 32 / 256, 256, 0, stream>>>(y, bns + 128, bn_g + 64, bn_b + 64, h);

    // dense head MLP (h is [4096,1024] row-major by construction)
    k_gemm<<<dim3(BB / GBM, 256 / GBN), 256, 0, stream>>>(h, mW1, mb1, X1, BB, 256, 1024, 1);
    k_gemm<<<dim3(BB / GBM, 256 / GBN), 256, 0, stream>>>(X1, mW2, mb2, X2, BB, 256, 256, 1);
    k_gemm<<<dim3(BB / GBM, 256 / GBN), 256, 0, stream>>>(X2, mW3, mb3, X1, BB, 256, 256, 1);

    // dueling heads
    k_head<<<BB, 64, 0, stream>>>(X1, vW, vb, aW, ab, out);
}

// Round 3
// 814.947 us; speedup vs baseline: 1.6159x; 1.5773x over previous
//
#include <hip/hip_runtime.h>

#define NN 131072        // nodes
#define EE 2097152       // edges
#define SS 32            // channels
#define HH 16            // hidden
#define BB 4096          // graphs
#define GB (NN / 16)     // gather blocks (8192)
#define EPS 1e-5f

// ---------------- CSR build: histogram, scan, scatter ----------------
__global__ __launch_bounds__(256) void k_hist(const int* __restrict__ ei, int* __restrict__ deg) {
    int e = blockIdx.x * 256 + threadIdx.x;
    if (e < EE) atomicAdd(&deg[ei[EE + e]], 1);
}

__global__ __launch_bounds__(256) void k_scan1(const int* __restrict__ deg, int* __restrict__ off,
                                               int* __restrict__ bsum) {
    __shared__ int s[256];
    int t = threadIdx.x;
    int base = blockIdx.x * 1024 + t * 4;
    int a0 = deg[base], a1 = deg[base + 1], a2 = deg[base + 2], a3 = deg[base + 3];
    int tot = a0 + a1 + a2 + a3;
    s[t] = tot;
    __syncthreads();
    for (int d = 1; d < 256; d <<= 1) {
        int v = (t >= d) ? s[t - d] : 0;
        __syncthreads();
        s[t] += v;
        __syncthreads();
    }
    int excl = s[t] - tot;
    if (t == 255) bsum[blockIdx.x] = s[255];
    off[base] = excl;
    off[base + 1] = excl + a0;
    off[base + 2] = excl + a0 + a1;
    off[base + 3] = excl + a0 + a1 + a2;
}

__global__ __launch_bounds__(128) void k_scan2(int* __restrict__ bsum) {
    __shared__ int s[128];
    int t = threadIdx.x;
    int val = bsum[t];
    s[t] = val;
    __syncthreads();
    for (int d = 1; d < 128; d <<= 1) {
        int v = (t >= d) ? s[t - d] : 0;
        __syncthreads();
        s[t] += v;
        __syncthreads();
    }
    bsum[t] = s[t] - val;   // exclusive
}

__global__ __launch_bounds__(256) void k_scan3(int* __restrict__ off, const int* __restrict__ bsum,
                                               int* __restrict__ cursor) {
    int t = threadIdx.x;
    int base = blockIdx.x * 1024 + t * 4;
    int addv = bsum[blockIdx.x];
#pragma unroll
    for (int i = 0; i < 4; ++i) {
        int v = off[base + i] + addv;
        off[base + i] = v;
        cursor[base + i] = v;
    }
    if (blockIdx.x == 0 && t == 0) off[NN] = EE;
}

__global__ __launch_bounds__(256) void k_scatter(const int* __restrict__ ei, int* __restrict__ cursor,
                                                 int* __restrict__ ssrc) {
    int e = blockIdx.x * 256 + threadIdx.x;
    if (e < EE) {
        int d = ei[EE + e];
        int p = atomicAdd(&cursor[d], 1);
        ssrc[p] = ei[e];
    }
}

// ---------------- per-node pre-transform (u = x@(Wt-Wb)+b1, v = x@Wb) ----------------
// v has NN+1 rows; row NN is a -1e30 dummy so padded gather slots contribute 0 after ReLU.
__global__ __launch_bounds__(256) void k_pre1(const float* __restrict__ x, const float* __restrict__ W1,
                                              const float* __restrict__ b1, float* __restrict__ u,
                                              float* __restrict__ v) {
    int t = blockIdx.x * 256 + threadIdx.x;     // N*16 threads
    int n = t >> 4, c = t & 15;
    float x0 = x[n * 2], x1 = x[n * 2 + 1];
    float w0 = W1[c], w1 = W1[16 + c], w2 = W1[32 + c], w3 = W1[48 + c];
    u[t] = b1[c] + x0 * (w0 - w2) + x1 * (w1 - w3);
    v[t] = x0 * w2 + x1 * w3;
    if (blockIdx.x == 0 && t < 16) v[NN * 16 + t] = -1e30f;   // dummy row
}

// layers 2/3: F=32 input features
__global__ __launch_bounds__(256) void k_pre32(const float* __restrict__ h, const float* __restrict__ W1,
                                               const float* __restrict__ b1, float* __restrict__ u,
                                               float* __restrict__ v) {
    __shared__ float sh[16][33];
    __shared__ float wd[32][16];
    __shared__ float wv[32][16];
    int t = threadIdx.x;
    for (int i = t; i < 512; i += 256) {
        int f = i >> 4, c = i & 15;
        float wt = W1[i];            // rows 0..31 (x_i part)
        float wb = W1[512 + i];      // rows 32..63 (x_j - x_i part)
        wd[f][c] = wt - wb;
        wv[f][c] = wb;
    }
    int nb = blockIdx.x * 16;
    for (int i = t; i < 512; i += 256) sh[i >> 5][i & 31] = h[nb * 32 + i];
    __syncthreads();
    int c = t & 15, nl = t >> 4;
    float uu = b1[c], vv = 0.f;
#pragma unroll
    for (int f = 0; f < 32; ++f) {
        float hv = sh[nl][f];
        uu += hv * wd[f][c];
        vv += hv * wv[f][c];
    }
    int n = nb + nl;
    u[n * 16 + c] = uu;
    v[n * 16 + c] = vv;
    if (blockIdx.x == 0 && t < 16) v[NN * 16 + t] = -1e30f;   // dummy row
}

// ---------------- gather (CSR reduce of ReLU(u[dst]+v[src])) + @W2 + BN partials ----------------
// BN stats go to per-block slots (coalesced stores, zero atomic contention);
// k_bnstat tree-reduces them. (R2 lesson: 524k same-line atomics = 211 us drain.)
__global__ __launch_bounds__(256) void k_gather(const float* __restrict__ u, const float* __restrict__ v,
                                                const int* __restrict__ ssrc, const int* __restrict__ off,
                                                const float* __restrict__ W2, const float* __restrict__ b2,
                                                float* __restrict__ y, float* __restrict__ part) {
    __shared__ float sw2[16][32];
    __shared__ float sagg[16][17];
    __shared__ float sy[32][17];
    int t = threadIdx.x;
    for (int i = t; i < 512; i += 256) sw2[i >> 5][i & 31] = W2[i];
    int c = t & 15, nl = t >> 4;
    int n = blockIdx.x * 16 + nl;
    int s0 = off[n], e0 = off[n + 1];
    float uc = u[n * 16 + c];
    float acc = 0.f;
    for (int p = s0; p < e0; p += 8) {
        int idx[8];
#pragma unroll
        for (int i = 0; i < 8; ++i) idx[i] = (p + i < e0) ? ssrc[p + i] : NN;
        float vv[8];
#pragma unroll
        for (int i = 0; i < 8; ++i) vv[i] = v[idx[i] * 16 + c];
#pragma unroll
        for (int i = 0; i < 8; ++i) acc += fmaxf(uc + vv[i], 0.f);
    }
    sagg[nl][c] = acc;
    __syncthreads();
    float cnt = (float)(e0 - s0);
    float y0 = b2[c] * cnt, y1 = b2[c + 16] * cnt;
#pragma unroll
    for (int k = 0; k < 16; ++k) {
        float a = sagg[nl][k];
        y0 += a * sw2[k][c];
        y1 += a * sw2[k][c + 16];
    }
    y[n * 32 + c] = y0;
    y[n * 32 + 16 + c] = y1;
    sy[c][nl] = y0;
    sy[c + 16][nl] = y1;
    __syncthreads();
    if (t < 32) {
        float sm = 0.f, sq = 0.f;
#pragma unroll
        for (int k2 = 0; k2 < 16; ++k2) {
            float w = sy[t][k2];
            sm += w;
            sq += w * w;
        }
        part[(size_t)blockIdx.x * 64 + t] = sm;
        part[(size_t)blockIdx.x * 64 + 32 + t] = sq;
    }
}

// ---------------- reduce per-block BN partials: [GB][64] -> [64] ----------------
__global__ __launch_bounds__(256) void k_bnstat(const float* __restrict__ part, float* __restrict__ bns) {
    __shared__ float s[256];
    int j = blockIdx.x;      // 0..63
    int t = threadIdx.x;
    float a = 0.f;
    for (int b = t; b < GB; b += 256) a += part[(size_t)b * 64 + j];
    s[t] = a;
    __syncthreads();
    for (int d = 128; d > 0; d >>= 1) {
        if (t < d) s[t] += s[t + d];
        __syncthreads();
    }
    if (t == 0) bns[j] = s[0];
}

// ---------------- BN (training-mode batch stats) + ReLU ----------------
__global__ __launch_bounds__(256) void k_bnrelu(const float* __restrict__ y, const float* __restrict__ bns,
                                                const float* __restrict__ g, const float* __restrict__ bb,
                                                float* __restrict__ h) {
    int t = blockIdx.x * 256 + threadIdx.x;
    int j = t & 31;
    const float inv_n = 1.0f / (float)NN;
    float mean = bns[j] * inv_n;
    float var = bns[32 + j] * inv_n - mean * mean;
    float sc = g[j] * rsqrtf(var + EPS);
    float sh = bb[j] - mean * sc;
    h[t] = fmaxf(y[t] * sc + sh, 0.f);
}

// ---------------- fp32 tiled GEMM: C = relu(A[M,K]@B[K,N] + bias) ----------------
#define GBM 64
#define GBN 64
#define GBK 16
__global__ __launch_bounds__(256) void k_gemm(const float* __restrict__ A, const float* __restrict__ Bm,
                                              const float* __restrict__ bias, float* __restrict__ C,
                                              int M, int Nc, int K, int relu) {
    __shared__ float As[GBK][GBM + 4];
    __shared__ float Bs[GBK][GBN + 4];
    int tid = threadIdx.x;
    int tx = tid & 15;
    int ty = tid >> 4;
    int rowBase = blockIdx.x * GBM;
    int colBase = blockIdx.y * GBN;
    int lr = tid >> 2;
    int lk = (tid & 3) * 4;
    int bkr = tid >> 4;
    int bc = (tid & 15) * 4;
    float acc[4][4] = {};
    for (int kt = 0; kt < K; kt += GBK) {
        float4 av = *(const float4*)(A + (size_t)(rowBase + lr) * K + kt + lk);
        As[lk + 0][lr] = av.x;
        As[lk + 1][lr] = av.y;
        As[lk + 2][lr] = av.z;
        As[lk + 3][lr] = av.w;
        float4 bv = *(const float4*)(Bm + (size_t)(kt + bkr) * Nc + colBase + bc);
        *(float4*)&Bs[bkr][bc] = bv;
        __syncthreads();
#pragma unroll
        for (int k = 0; k < GBK; ++k) {
            float4 ar = *(const float4*)&As[k][ty * 4];
            float4 br = *(const float4*)&Bs[k][tx * 4];
            acc[0][0] += ar.x * br.x; acc[0][1] += ar.x * br.y; acc[0][2] += ar.x * br.z; acc[0][3] += ar.x * br.w;
            acc[1][0] += ar.y * br.x; acc[1][1] += ar.y * br.y; acc[1][2] += ar.y * br.z; acc[1][3] += ar.y * br.w;
            acc[2][0] += ar.z * br.x; acc[2][1] += ar.z * br.y; acc[2][2] += ar.z * br.z; acc[2][3] += ar.z * br.w;
            acc[3][0] += ar.w * br.x; acc[3][1] += ar.w * br.y; acc[3][2] += ar.w * br.z; acc[3][3] += ar.w * br.w;
        }
        __syncthreads();
    }
    float b0 = bias[colBase + tx * 4 + 0];
    float b1 = bias[colBase + tx * 4 + 1];
    float b2 = bias[colBase + tx * 4 + 2];
    float b3 = bias[colBase + tx * 4 + 3];
#pragma unroll
    for (int i = 0; i < 4; ++i) {
        int row = rowBase + ty * 4 + i;
        float4 o;
        o.x = acc[i][0] + b0;
        o.y = acc[i][1] + b1;
        o.z = acc[i][2] + b2;
        o.w = acc[i][3] + b3;
        if (relu) {
            o.x = fmaxf(o.x, 0.f); o.y = fmaxf(o.y, 0.f);
            o.z = fmaxf(o.z, 0.f); o.w = fmaxf(o.w, 0.f);
        }
        *(float4*)(C + (size_t)row * Nc + colBase + tx * 4) = o;
    }
}

// ---------------- dueling head: value + adv - adv.mean ----------------
__global__ __launch_bounds__(64) void k_head(const float* __restrict__ X, const float* __restrict__ vW,
                                             const float* __restrict__ vb, const float* __restrict__ aW,
                                             const float* __restrict__ ab, float* __restrict__ out) {
    __shared__ float s[256];
    __shared__ float sval;
    int b = blockIdx.x, t = threadIdx.x;
    float4 xv = *(const float4*)(X + (size_t)b * 256 + t * 4);
    *(float4*)&s[t * 4] = xv;
    float pv = xv.x * vW[t * 4] + xv.y * vW[t * 4 + 1] + xv.z * vW[t * 4 + 2] + xv.w * vW[t * 4 + 3];
#pragma unroll
    for (int d = 32; d > 0; d >>= 1) pv += __shfl_down(pv, d, 64);
    if (t == 0) sval = pv + vb[0];
    __syncthreads();
    int n = t >> 1, a = t & 1;
    const float* wp = aW + n * 512 + a;
    float acc = 0.f;
#pragma unroll 8
    for (int f = 0; f < 256; ++f) acc += s[f] * wp[f * 2];
    float adv = acc + ab[n * 2 + a];
    float other = __shfl_xor(adv, 1, 64);
    out[(size_t)b * 64 + t] = sval + 0.5f * (adv - other);
}

extern "C" void kernel_launch(void* const* d_in, const int* in_sizes, int n_in,
                              void* d_out, int out_size, void* d_ws, size_t ws_size,
                              hipStream_t stream) {
    const float* x    = (const float*)d_in[0];
    const int*   ei   = (const int*)d_in[1];
    const float* c1W1 = (const float*)d_in[2];
    const float* c1b1 = (const float*)d_in[3];
    const float* c1W2 = (const float*)d_in[4];
    const float* c1b2 = (const float*)d_in[5];
    const float* c2W1 = (const float*)d_in[6];
    const float* c2b1 = (const float*)d_in[7];
    const float* c2W2 = (const float*)d_in[8];
    const float* c2b2 = (const float*)d_in[9];
    const float* c3W1 = (const float*)d_in[10];
    const float* c3b1 = (const float*)d_in[11];
    const float* c3W2 = (const float*)d_in[12];
    const float* c3b2 = (const float*)d_in[13];
    const float* bn_g = (const float*)d_in[14];
    const float* bn_b = (const float*)d_in[15];
    const float* mW1  = (const float*)d_in[16];
    const float* mb1  = (const float*)d_in[17];
    const float* mW2  = (const float*)d_in[18];
    const float* mb2  = (const float*)d_in[19];
    const float* mW3  = (const float*)d_in[20];
    const float* mb3  = (const float*)d_in[21];
    const float* vW   = (const float*)d_in[22];
    const float* vb   = (const float*)d_in[23];
    const float* aW   = (const float*)d_in[24];
    const float* ab   = (const float*)d_in[25];
    float* out = (float*)d_out;

    char* p = (char*)d_ws;
    auto take = [&](size_t bytes) {
        char* r = p;
        p += (bytes + 255) & ~(size_t)255;
        return r;
    };
    int*   deg    = (int*)take((size_t)NN * 4);
    int*   off    = (int*)take((size_t)(NN + 1) * 4);
    int*   bsum   = (int*)take(512);
    int*   cursor = (int*)take((size_t)NN * 4);
    int*   ssrc   = (int*)take((size_t)EE * 4);
    float* u      = (float*)take((size_t)NN * HH * 4);
    float* v      = (float*)take((size_t)(NN + 1) * HH * 4);   // +1 dummy row
    float* y      = (float*)take((size_t)NN * SS * 4);
    float* h      = (float*)take((size_t)NN * SS * 4);
    float* bns    = (float*)take(3 * 64 * 4);
    float* part   = (float*)take((size_t)GB * 64 * 4);         // BN partials, 2 MB
    // X1/X2 reuse the y buffer (dead after last bn_relu): 4096*256*4 = 4 MB each
    float* X1 = y;
    float* X2 = y + (size_t)BB * 256;

    hipMemsetAsync(deg, 0, (size_t)NN * 4, stream);

    // CSR build (reused by all 3 conv layers)
    k_hist<<<EE / 256, 256, 0, stream>>>(ei, deg);
    k_scan1<<<128, 256, 0, stream>>>(deg, off, bsum);
    k_scan2<<<1, 128, 0, stream>>>(bsum);
    k_scan3<<<128, 256, 0, stream>>>(off, bsum, cursor);
    k_scatter<<<EE / 256, 256, 0, stream>>>(ei, cursor, ssrc);

    // layer 1
    k_pre1<<<NN * 16 / 256, 256, 0, stream>>>(x, c1W1, c1b1, u, v);
    k_gather<<<GB, 256, 0, stream>>>(u, v, ssrc, off, c1W2, c1b2, y, part);
    k_bnstat<<<64, 256, 0, stream>>>(part, bns);
    k_bnrelu<<<NN * 32 / 256, 256, 0, stream>>>(y, bns, bn_g, bn_b, h);
    // layer 2
    k_pre32<<<NN / 16, 256, 0, stream>>>(h, c2W1, c2b1, u, v);
    k_gather<<<GB, 256, 0, stream>>>(u, v, ssrc, off, c2W2, c2b2, y, part);
    k_bnstat<<<64, 256, 0, stream>>>(part, bns + 64);
    k_bnrelu<<<NN * 32 / 256, 256, 0, stream>>>(y, bns + 64, bn_g + 32, bn_b + 32, h);
    // layer 3
    k_pre32<<<NN / 16, 256, 0, stream>>>(h, c3W1, c3b1, u, v);
    k_gather<<<GB, 256, 0, stream>>>(u, v, ssrc, off, c3W2, c3b2, y, part);
    k_bnstat<<<64, 256, 0, stream>>>(part, bns + 128);
    k_bnrelu<<<NN * 32 / 256, 256, 0, stream>>>(y, bns + 128, bn_g + 64, bn_b + 64, h);

    // dense head MLP (h is [4096,1024] row-major by construction)
    k_gemm<<<dim3(BB / GBM, 256 / GBN), 256, 0, stream>>>(h, mW1, mb1, X1, BB, 256, 1024, 1);
    k_gemm<<<dim3(BB / GBM, 256 / GBN), 256, 0, stream>>>(X1, mW2, mb2, X2, BB, 256, 256, 1);
    k_gemm<<<dim3(BB / GBM, 256 / GBN), 256, 0, stream>>>(X2, mW3, mb3, X1, BB, 256, 256, 1);

    // dueling heads
    k_head<<<BB, 64, 0, stream>>>(X1, vW, vb, aW, ab, out);
}